// Round 2
// baseline (127.229 us; speedup 1.0000x reference)
//
#include <hip/hip_runtime.h>
#include <math.h>

#define NUM_CLASSES 16
#define MARGIN_F 0.3f
#define EPS_F 1e-8f

// ws layout (as float*):
//   [0..255]   : D16 distance matrix (row-major, D16[c1*16+c2])
//   [256..271] : present flags (1.0f / 0.0f)
//   [272..274] : accumulators {rank_sum, per_sum, valid_cnt}
//   [275]      : block completion counter (as int)

// kA: one block, 1024 threads.
// Phase 1: first-occurrence index per class (LDS atomicMin over targets).
// Phase 2a: wave w computes sq[w] = ||x_first[w]||^2 (16 waves = 16 classes).
// Phase 2b: each wave computes 16 of the 256 pair dots; D16 = sqrt(sq1+sq2-2dot).
__global__ __launch_bounds__(1024) void kA(const float* __restrict__ x, int Dm,
                                           const int* __restrict__ targets, int B,
                                           float* __restrict__ D16,
                                           float* __restrict__ wsPres,
                                           float* __restrict__ wsAcc,
                                           int* __restrict__ wsCnt) {
    __shared__ int   fi[NUM_CLASSES];
    __shared__ float sSq[NUM_CLASSES];
    int t = threadIdx.x;
    if (t < NUM_CLASSES) fi[t] = 0x7fffffff;
    __syncthreads();
    for (int j = t; j < B; j += 1024) {
        int c = targets[j];
        if (c >= 0 && c < NUM_CLASSES) atomicMin(&fi[c], j);
    }
    __syncthreads();
    if (t < NUM_CLASSES) {
        int v = fi[t];
        int pres = (v != 0x7fffffff);
        wsPres[t] = pres ? 1.0f : 0.0f;
        fi[t] = pres ? v : 0;          // argmax over all-False returns 0
    }
    if (t < 3) wsAcc[t] = 0.0f;        // ws poisoned 0xAA each call — must zero
    if (t == 3) *wsCnt = 0;
    __syncthreads();

    int wave = t >> 6, lane = t & 63;

    // Phase 2a: sq per class, one wave per class.
    {
        const float* __restrict__ row = x + (long)fi[wave] * Dm;
        float s = 0.f;
        for (int k = lane; k < Dm; k += 64) { float a = row[k]; s = fmaf(a, a, s); }
        #pragma unroll
        for (int off = 32; off > 0; off >>= 1) s += __shfl_down(s, off);
        if (lane == 0) sSq[wave] = s;
    }
    __syncthreads();

    // Phase 2b: 16 pairs per wave.
    for (int pair = wave; pair < 256; pair += 16) {
        int c1 = pair >> 4, c2 = pair & 15;
        const float* __restrict__ x1 = x + (long)fi[c1] * Dm;
        const float* __restrict__ x2 = x + (long)fi[c2] * Dm;
        float dot = 0.f;
        for (int k = lane; k < Dm; k += 64) dot = fmaf(x1[k], x2[k], dot);
        #pragma unroll
        for (int off = 32; off > 0; off >>= 1) dot += __shfl_down(dot, off);
        if (lane == 0) {
            float d2 = sSq[c1] + sSq[c2] - 2.0f * dot;  // c1==c2 -> exactly 0
            D16[pair] = sqrtf(fmaxf(d2, 1e-12f));
        }
    }
}

// kB: triple reduction + last-block finalize.
__global__ __launch_bounds__(256) void kB(const int* __restrict__ ua, int T,
                                          const float* __restrict__ D16,
                                          const float* __restrict__ wsPres,
                                          float* __restrict__ wsAcc,
                                          int* __restrict__ wsCnt,
                                          float* __restrict__ out) {
    __shared__ float sD[256];
    __shared__ float sP[NUM_CLASSES];
    __shared__ float sRed[4][3];
    __shared__ bool  amLast;
    int t = threadIdx.x;
    sD[t] = D16[t];
    if (t < NUM_CLASSES) sP[t] = wsPres[t];
    __syncthreads();

    float r = 0.f, pp = 0.f, cnt = 0.f;
    for (int i = blockIdx.x * blockDim.x + t; i < T; i += gridDim.x * blockDim.x) {
        int a = ua[3 * i + 0];
        int b = ua[3 * i + 1];
        int c = ua[3 * i + 2];
        float valid = sP[a] * sP[b] * sP[c];
        float dap = sD[(a << 4) | b];
        float dan = sD[(a << 4) | c];
        float rank = fmaxf(dap - dan + MARGIN_F, 0.0f);
        float sap = 1.0f / (dap + 1.0f);
        float san = 1.0f / (dan + 1.0f);
        float per = -logf(sap / (sap + san) + EPS_F);
        r   += valid * rank;
        pp  += valid * per;
        cnt += valid;
    }
    #pragma unroll
    for (int off = 32; off > 0; off >>= 1) {
        r   += __shfl_down(r, off);
        pp  += __shfl_down(pp, off);
        cnt += __shfl_down(cnt, off);
    }
    int wave = t >> 6, lane = t & 63;
    if (lane == 0) { sRed[wave][0] = r; sRed[wave][1] = pp; sRed[wave][2] = cnt; }
    __syncthreads();
    if (t == 0) {
        float R = 0.f, P = 0.f, C = 0.f;
        #pragma unroll
        for (int w = 0; w < 4; ++w) { R += sRed[w][0]; P += sRed[w][1]; C += sRed[w][2]; }
        atomicAdd(&wsAcc[0], R);
        atomicAdd(&wsAcc[1], P);
        atomicAdd(&wsAcc[2], C);
        __threadfence();                       // make adds visible before counter bump
        int done = atomicAdd(wsCnt, 1);
        amLast = (done == (int)gridDim.x - 1);
    }
    __syncthreads();
    if (amLast && t == 0) {
        // coherent reads via device-scope atomic no-op adds
        float R  = atomicAdd(&wsAcc[0], 0.0f);
        float P  = atomicAdd(&wsAcc[1], 0.0f);
        float C  = atomicAdd(&wsAcc[2], 0.0f);
        float nv = fmaxf(C, 1.0f);
        float lh = R / nv;
        float lp = P / nv;
        out[0] = lh + lp;
        out[1] = lh;
        out[2] = lp;
    }
}

extern "C" void kernel_launch(void* const* d_in, const int* in_sizes, int n_in,
                              void* d_out, int out_size, void* d_ws, size_t ws_size,
                              hipStream_t stream) {
    // setup_inputs order:
    // 0: preds_mat (unused)  1: preds_sub (unused)  2: inputs (B,D) f32
    // 3: targets_mat (B,) int  4: targets_sub (unused)  5: user_answers (T,3) int
    const float* x       = (const float*)d_in[2];
    const int*   targets = (const int*)d_in[3];
    const int*   ua      = (const int*)d_in[5];
    float* out = (float*)d_out;

    int B  = in_sizes[3];
    int Dm = in_sizes[2] / B;
    int T  = in_sizes[5] / 3;

    float* ws     = (float*)d_ws;
    float* D16    = ws;              // 256 floats
    float* wsPres = ws + 256;        // 16 floats
    float* wsAcc  = ws + 272;        // 3 floats
    int*   wsCnt  = (int*)(ws + 275);

    kA<<<1, 1024, 0, stream>>>(x, Dm, targets, B, D16, wsPres, wsAcc, wsCnt);
    kB<<<256, 256, 0, stream>>>(ua, T, D16, wsPres, wsAcc, wsCnt, out);
}

// Round 3
// 99.169 us; speedup vs baseline: 1.2829x; 1.2829x over previous
//
#include <hip/hip_runtime.h>
#include <math.h>

#define NUM_CLASSES 16
#define MARGIN_F 0.3f
#define EPS_F 1e-8f

// ws layout (as float*):
//   [0..255]   : D16 distance matrix (row-major, D16[c1*16+c2])
//   [256..271] : first_idx (int)
//   [272..287] : present flags (1.0f / 0.0f)
//   [288..290] : accumulators {rank_sum, per_sum, valid_cnt}
//   [291]      : block completion counter (int)

// k_first: 1 block x 256. Ballot-based first-occurrence scan (avoids 4096
// contended LDS atomics: 16 v_cmp/ballot per 64-chunk, ~256 atomics total).
__global__ __launch_bounds__(256) void k_first(const int* __restrict__ targets, int B,
                                               int* __restrict__ wsFirst,
                                               float* __restrict__ wsPres,
                                               float* __restrict__ wsAcc,
                                               int* __restrict__ wsCnt) {
    __shared__ int fi[NUM_CLASSES];
    int t = threadIdx.x;
    if (t < NUM_CLASSES) fi[t] = 0x7fffffff;
    if (t >= 32 && t < 35) wsAcc[t - 32] = 0.0f;  // ws poisoned 0xAA — must zero
    if (t == 35) *wsCnt = 0;
    __syncthreads();

    int lane = t & 63;
    int waveBase = t & ~63;          // wave_id * 64
    int myMin = 0x7fffffff;          // lane c (<16) tracks class c
    for (int base = waveBase; base < B; base += 256) {
        int v = (base + lane < B) ? targets[base + lane] : -1;
        #pragma unroll
        for (int c = 0; c < NUM_CLASSES; ++c) {
            unsigned long long m = __ballot(v == c);
            if (lane == c && m != 0ULL) {
                int cand = base + (__ffsll((long long)m) - 1);
                myMin = min(myMin, cand);
            }
        }
    }
    if (lane < NUM_CLASSES && myMin != 0x7fffffff) atomicMin(&fi[lane], myMin);
    __syncthreads();
    if (t < NUM_CLASSES) {
        int v = fi[t];
        int pres = (v != 0x7fffffff);
        wsPres[t]  = pres ? 1.0f : 0.0f;
        wsFirst[t] = pres ? v : 0;   // argmax over all-False returns 0
    }
}

// k_dist: 256 blocks x 256 threads, one (c1,c2) pair per block.
// Dm=1024 -> exactly one float4 per lane per row; shuffle+LDS reduce.
__global__ __launch_bounds__(256) void k_dist(const float* __restrict__ x, int Dm,
                                              const int* __restrict__ wsFirst,
                                              float* __restrict__ D16) {
    __shared__ float red[4][3];
    int pair = blockIdx.x;
    int c1 = pair >> 4, c2 = pair & 15;
    const float4* __restrict__ x1 = (const float4*)(x + (long)wsFirst[c1] * Dm);
    const float4* __restrict__ x2 = (const float4*)(x + (long)wsFirst[c2] * Dm);
    int t = threadIdx.x;
    int n4 = Dm >> 2;
    float dot = 0.f, s1 = 0.f, s2 = 0.f;
    for (int k = t; k < n4; k += 256) {
        float4 a = x1[k], b = x2[k];
        dot = fmaf(a.x, b.x, fmaf(a.y, b.y, fmaf(a.z, b.z, fmaf(a.w, b.w, dot))));
        s1  = fmaf(a.x, a.x, fmaf(a.y, a.y, fmaf(a.z, a.z, fmaf(a.w, a.w, s1))));
        s2  = fmaf(b.x, b.x, fmaf(b.y, b.y, fmaf(b.z, b.z, fmaf(b.w, b.w, s2))));
    }
    #pragma unroll
    for (int off = 32; off > 0; off >>= 1) {
        dot += __shfl_down(dot, off);
        s1  += __shfl_down(s1, off);
        s2  += __shfl_down(s2, off);
    }
    int wave = t >> 6, lane = t & 63;
    if (lane == 0) { red[wave][0] = dot; red[wave][1] = s1; red[wave][2] = s2; }
    __syncthreads();
    if (t == 0) {
        float D = 0.f, A = 0.f, Bq = 0.f;
        #pragma unroll
        for (int w = 0; w < 4; ++w) { D += red[w][0]; A += red[w][1]; Bq += red[w][2]; }
        float d2 = A + Bq - 2.0f * D;        // c1==c2 -> exactly 0 (identical sequences)
        D16[pair] = sqrtf(fmaxf(d2, 1e-12f));
    }
}

// kB: triple reduction + last-block finalize.
__global__ __launch_bounds__(256) void kB(const int* __restrict__ ua, int T,
                                          const float* __restrict__ D16,
                                          const float* __restrict__ wsPres,
                                          float* __restrict__ wsAcc,
                                          int* __restrict__ wsCnt,
                                          float* __restrict__ out) {
    __shared__ float sD[256];
    __shared__ float sP[NUM_CLASSES];
    __shared__ float sRed[4][3];
    __shared__ bool  amLast;
    int t = threadIdx.x;
    sD[t] = D16[t];
    if (t < NUM_CLASSES) sP[t] = wsPres[t];
    __syncthreads();

    float r = 0.f, pp = 0.f, cnt = 0.f;
    for (int i = blockIdx.x * blockDim.x + t; i < T; i += gridDim.x * blockDim.x) {
        int a = ua[3 * i + 0];
        int b = ua[3 * i + 1];
        int c = ua[3 * i + 2];
        float valid = sP[a] * sP[b] * sP[c];
        float dap = sD[(a << 4) | b];
        float dan = sD[(a << 4) | c];
        float rank = fmaxf(dap - dan + MARGIN_F, 0.0f);
        float sap = 1.0f / (dap + 1.0f);
        float san = 1.0f / (dan + 1.0f);
        float per = -logf(sap / (sap + san) + EPS_F);
        r   += valid * rank;
        pp  += valid * per;
        cnt += valid;
    }
    #pragma unroll
    for (int off = 32; off > 0; off >>= 1) {
        r   += __shfl_down(r, off);
        pp  += __shfl_down(pp, off);
        cnt += __shfl_down(cnt, off);
    }
    int wave = t >> 6, lane = t & 63;
    if (lane == 0) { sRed[wave][0] = r; sRed[wave][1] = pp; sRed[wave][2] = cnt; }
    __syncthreads();
    if (t == 0) {
        float R = 0.f, P = 0.f, C = 0.f;
        #pragma unroll
        for (int w = 0; w < 4; ++w) { R += sRed[w][0]; P += sRed[w][1]; C += sRed[w][2]; }
        atomicAdd(&wsAcc[0], R);
        atomicAdd(&wsAcc[1], P);
        atomicAdd(&wsAcc[2], C);
        __threadfence();
        int done = atomicAdd(wsCnt, 1);
        amLast = (done == (int)gridDim.x - 1);
    }
    __syncthreads();
    if (amLast && t == 0) {
        float R  = atomicAdd(&wsAcc[0], 0.0f);   // coherent device-scope reads
        float P  = atomicAdd(&wsAcc[1], 0.0f);
        float C  = atomicAdd(&wsAcc[2], 0.0f);
        float nv = fmaxf(C, 1.0f);
        float lh = R / nv;
        float lp = P / nv;
        out[0] = lh + lp;
        out[1] = lh;
        out[2] = lp;
    }
}

extern "C" void kernel_launch(void* const* d_in, const int* in_sizes, int n_in,
                              void* d_out, int out_size, void* d_ws, size_t ws_size,
                              hipStream_t stream) {
    // setup_inputs order:
    // 0: preds_mat (unused)  1: preds_sub (unused)  2: inputs (B,D) f32
    // 3: targets_mat (B,) int  4: targets_sub (unused)  5: user_answers (T,3) int
    const float* x       = (const float*)d_in[2];
    const int*   targets = (const int*)d_in[3];
    const int*   ua      = (const int*)d_in[5];
    float* out = (float*)d_out;

    int B  = in_sizes[3];
    int Dm = in_sizes[2] / B;
    int T  = in_sizes[5] / 3;

    float* ws      = (float*)d_ws;
    float* D16     = ws;                  // 256 floats
    int*   wsFirst = (int*)(ws + 256);    // 16 ints
    float* wsPres  = ws + 272;            // 16 floats
    float* wsAcc   = ws + 288;            // 3 floats
    int*   wsCnt   = (int*)(ws + 291);

    k_first<<<1, 256, 0, stream>>>(targets, B, wsFirst, wsPres, wsAcc, wsCnt);
    k_dist<<<256, 256, 0, stream>>>(x, Dm, wsFirst, D16);
    kB<<<256, 256, 0, stream>>>(ua, T, D16, wsPres, wsAcc, wsCnt, out);
}

// Round 4
// 98.865 us; speedup vs baseline: 1.2869x; 1.0031x over previous
//
#include <hip/hip_runtime.h>
#include <math.h>

#define NUM_CLASSES 16
#define MARGIN_F 0.3f
#define EPS_F 1e-8f

// ws layout (as float*):
//   [0..255]   : D16 distance matrix (row-major, D16[c1*16+c2])
//   [256..271] : present flags (1.0f / 0.0f)
//   [272..274] : accumulators {rank_sum, per_sum, valid_cnt}
//   [275]      : block completion counter (int)

// k_dist: 256 blocks x 256 threads. Each block REDUNDANTLY ballot-scans
// targets for first-occurrence indices (16 KB, L2-broadcast, ~0.4 us),
// then computes its one (c1,c2) pair distance. Fusing the scan here removes
// a whole graph node vs the 3-kernel version.
__global__ __launch_bounds__(256) void k_dist(const float* __restrict__ x, int Dm,
                                              const int* __restrict__ targets, int B,
                                              float* __restrict__ D16,
                                              float* __restrict__ wsPres,
                                              float* __restrict__ wsAcc,
                                              int* __restrict__ wsCnt) {
    __shared__ int   fi[NUM_CLASSES];
    __shared__ float red[4][3];
    int t = threadIdx.x;
    if (t < NUM_CLASSES) fi[t] = 0x7fffffff;
    __syncthreads();

    // Ballot-based first-occurrence scan (16 cmp/ballot per 64-chunk).
    int lane = t & 63;
    int waveBase = t & ~63;
    int myMin = 0x7fffffff;            // lane c (<16) tracks class c
    for (int base = waveBase; base < B; base += 256) {
        int v = (base + lane < B) ? targets[base + lane] : -1;
        #pragma unroll
        for (int c = 0; c < NUM_CLASSES; ++c) {
            unsigned long long m = __ballot(v == c);
            if (lane == c && m != 0ULL) {
                int cand = base + (__ffsll((long long)m) - 1);
                myMin = min(myMin, cand);
            }
        }
    }
    if (lane < NUM_CLASSES && myMin != 0x7fffffff) atomicMin(&fi[lane], myMin);
    __syncthreads();

    // Block 0 publishes present flags and zeroes accumulators (ws poisoned 0xAA).
    if (blockIdx.x == 0) {
        if (t < NUM_CLASSES) wsPres[t] = (fi[t] != 0x7fffffff) ? 1.0f : 0.0f;
        if (t >= 32 && t < 35) wsAcc[t - 32] = 0.0f;
        if (t == 35) *wsCnt = 0;
    }

    // Pair distance: Dm=1024 -> exactly one float4 per lane per row.
    int pair = blockIdx.x;
    int c1 = pair >> 4, c2 = pair & 15;
    int i1 = fi[c1], i2 = fi[c2];
    if (i1 == 0x7fffffff) i1 = 0;      // argmax over all-False returns 0
    if (i2 == 0x7fffffff) i2 = 0;
    const float4* __restrict__ x1 = (const float4*)(x + (long)i1 * Dm);
    const float4* __restrict__ x2 = (const float4*)(x + (long)i2 * Dm);
    int n4 = Dm >> 2;
    float dot = 0.f, s1 = 0.f, s2 = 0.f;
    for (int k = t; k < n4; k += 256) {
        float4 a = x1[k], b = x2[k];
        dot = fmaf(a.x, b.x, fmaf(a.y, b.y, fmaf(a.z, b.z, fmaf(a.w, b.w, dot))));
        s1  = fmaf(a.x, a.x, fmaf(a.y, a.y, fmaf(a.z, a.z, fmaf(a.w, a.w, s1))));
        s2  = fmaf(b.x, b.x, fmaf(b.y, b.y, fmaf(b.z, b.z, fmaf(b.w, b.w, s2))));
    }
    #pragma unroll
    for (int off = 32; off > 0; off >>= 1) {
        dot += __shfl_down(dot, off);
        s1  += __shfl_down(s1, off);
        s2  += __shfl_down(s2, off);
    }
    int wave = t >> 6;
    if (lane == 0) { red[wave][0] = dot; red[wave][1] = s1; red[wave][2] = s2; }
    __syncthreads();
    if (t == 0) {
        float D = 0.f, A = 0.f, Bq = 0.f;
        #pragma unroll
        for (int w = 0; w < 4; ++w) { D += red[w][0]; A += red[w][1]; Bq += red[w][2]; }
        float d2 = A + Bq - 2.0f * D;  // c1==c2 -> exactly 0 (identical FMA sequences)
        D16[pair] = sqrtf(fmaxf(d2, 1e-12f));
    }
}

// kB: triple reduction + last-block finalize.
__global__ __launch_bounds__(256) void kB(const int* __restrict__ ua, int T,
                                          const float* __restrict__ D16,
                                          const float* __restrict__ wsPres,
                                          float* __restrict__ wsAcc,
                                          int* __restrict__ wsCnt,
                                          float* __restrict__ out) {
    __shared__ float sD[256];
    __shared__ float sP[NUM_CLASSES];
    __shared__ float sRed[4][3];
    __shared__ bool  amLast;
    int t = threadIdx.x;
    sD[t] = D16[t];
    if (t < NUM_CLASSES) sP[t] = wsPres[t];
    __syncthreads();

    float r = 0.f, pp = 0.f, cnt = 0.f;
    for (int i = blockIdx.x * blockDim.x + t; i < T; i += gridDim.x * blockDim.x) {
        int a = ua[3 * i + 0];
        int b = ua[3 * i + 1];
        int c = ua[3 * i + 2];
        float valid = sP[a] * sP[b] * sP[c];
        float dap = sD[(a << 4) | b];
        float dan = sD[(a << 4) | c];
        float rank = fmaxf(dap - dan + MARGIN_F, 0.0f);
        float sap = 1.0f / (dap + 1.0f);
        float san = 1.0f / (dan + 1.0f);
        float per = -logf(sap / (sap + san) + EPS_F);
        r   += valid * rank;
        pp  += valid * per;
        cnt += valid;
    }
    #pragma unroll
    for (int off = 32; off > 0; off >>= 1) {
        r   += __shfl_down(r, off);
        pp  += __shfl_down(pp, off);
        cnt += __shfl_down(cnt, off);
    }
    int wave = t >> 6, lane = t & 63;
    if (lane == 0) { sRed[wave][0] = r; sRed[wave][1] = pp; sRed[wave][2] = cnt; }
    __syncthreads();
    if (t == 0) {
        float R = 0.f, P = 0.f, C = 0.f;
        #pragma unroll
        for (int w = 0; w < 4; ++w) { R += sRed[w][0]; P += sRed[w][1]; C += sRed[w][2]; }
        atomicAdd(&wsAcc[0], R);
        atomicAdd(&wsAcc[1], P);
        atomicAdd(&wsAcc[2], C);
        __threadfence();
        int done = atomicAdd(wsCnt, 1);
        amLast = (done == (int)gridDim.x - 1);
    }
    __syncthreads();
    if (amLast && t == 0) {
        float R  = atomicAdd(&wsAcc[0], 0.0f);   // coherent device-scope reads
        float P  = atomicAdd(&wsAcc[1], 0.0f);
        float C  = atomicAdd(&wsAcc[2], 0.0f);
        float nv = fmaxf(C, 1.0f);
        float lh = R / nv;
        float lp = P / nv;
        out[0] = lh + lp;
        out[1] = lh;
        out[2] = lp;
    }
}

extern "C" void kernel_launch(void* const* d_in, const int* in_sizes, int n_in,
                              void* d_out, int out_size, void* d_ws, size_t ws_size,
                              hipStream_t stream) {
    // setup_inputs order:
    // 0: preds_mat (unused)  1: preds_sub (unused)  2: inputs (B,D) f32
    // 3: targets_mat (B,) int  4: targets_sub (unused)  5: user_answers (T,3) int
    const float* x       = (const float*)d_in[2];
    const int*   targets = (const int*)d_in[3];
    const int*   ua      = (const int*)d_in[5];
    float* out = (float*)d_out;

    int B  = in_sizes[3];
    int Dm = in_sizes[2] / B;
    int T  = in_sizes[5] / 3;

    float* ws     = (float*)d_ws;
    float* D16    = ws;              // 256 floats
    float* wsPres = ws + 256;        // 16 floats
    float* wsAcc  = ws + 272;        // 3 floats
    int*   wsCnt  = (int*)(ws + 275);

    k_dist<<<256, 256, 0, stream>>>(x, Dm, targets, B, D16, wsPres, wsAcc, wsCnt);
    kB<<<256, 256, 0, stream>>>(ua, T, D16, wsPres, wsAcc, wsCnt, out);
}